// Round 3
// baseline (1142.166 us; speedup 1.0000x reference)
//
#include <hip/hip_runtime.h>
#include <hip/hip_bf16.h>

// Encoder: attention-weighted LSTM, B=32768 T=9 D_IN=81 H=128.
// All inputs AND outputs fp32 (round-1 NaN => inputs fp32; round-2
// misalignment error 0.159 > max|ref| => outputs fp32 too).
// Key simplification: logits = pre + scalar(b) broadcast over softmax axis
// => attn = softmax(pre) is time-invariant; Wh/Wc are dead parameters.
// Recurrence reduces to gates_t = [w_in_t | h_t] @ [W_ih | W_hh]^T + bias.

namespace {

constexpr int kB    = 32768;
constexpr int kT    = 9;
constexpr int kD    = 81;     // D_IN
constexpr int kH    = 128;
constexpr int kG    = 512;    // 4H
constexpr int kK    = 209;    // 81 + 128
constexpr int kKPad = 224;    // padded to 14 chunks of 16 (pad rows zeroed)
constexpr int kNB   = 32;     // batch rows per block
constexpr int kKC   = 16;     // K rows staged in LDS per chunk
constexpr int kTh   = 256;    // threads per block
constexpr int kAStr = 36;     // actT row stride in floats (32 + 4 pad)

// ws layout: [W_t bf16 [kKPad][512] gate-permuted cols][bias 512 f32][Wx 16 f32][b_attn f32]
constexpr int kWsWtBytes  = kKPad * kG * 2;      // 229376
constexpr int kWsBiasOff  = kWsWtBytes;
constexpr int kWsWxOff    = kWsBiasOff + kG * 4;
constexpr int kWsBAttnOff = kWsWxOff + 16 * 4;

__device__ __forceinline__ float bflo(unsigned v) { return __uint_as_float(v << 16); }
__device__ __forceinline__ float bfhi(unsigned v) { return __uint_as_float(v & 0xffff0000u); }

__device__ __forceinline__ float sigf(float x) {
  return __builtin_amdgcn_rcpf(1.f + __expf(-x));
}
// tanh(x) = 1 - 2/(1+e^{2x}); saturates correctly as exp -> 0/inf
__device__ __forceinline__ float tanhfast(float x) {
  return 1.f - 2.f * __builtin_amdgcn_rcpf(1.f + __expf(2.f * x));
}

// ---- prep: repack weights (fp32 in, bf16 staged). col permutation p = u*4+q
// (g = q*128 + u) so one thread's 8 contiguous cols = {i,f,g,o}x{u0,u0+1}.
__global__ void prep_kernel(const float* __restrict__ W_attn,
                            const float* __restrict__ b_attn,
                            const float* __restrict__ W_ih,
                            const float* __restrict__ W_hh,
                            const float* __restrict__ b_ih,
                            const float* __restrict__ b_hh,
                            unsigned char* __restrict__ ws) {
  __hip_bfloat16* Wt = reinterpret_cast<__hip_bfloat16*>(ws);
  float* biasp = reinterpret_cast<float*>(ws + kWsBiasOff);
  float* wxp   = reinterpret_cast<float*>(ws + kWsWxOff);
  float* bap   = reinterpret_cast<float*>(ws + kWsBAttnOff);
  int tid = blockIdx.x * blockDim.x + threadIdx.x;
  int nth = gridDim.x * blockDim.x;
  for (int idx = tid; idx < kKPad * kG; idx += nth) {
    int k = idx >> 9, p = idx & 511;
    int u = p >> 2, q = p & 3, g = q * kH + u;
    float v = 0.f;
    if (k < kD)      v = W_ih[g * kD + k];
    else if (k < kK) v = W_hh[g * kH + (k - kD)];
    Wt[idx] = __float2bfloat16(v);
  }
  if (tid < kG) {
    int u = tid >> 2, q = tid & 3, g = q * kH + u;
    biasp[tid] = b_ih[g] + b_hh[g];
  }
  if (tid >= kG && tid < kG + 16) {
    int t = tid - kG;
    wxp[t] = (t < kT) ? W_attn[2 * kH + t] : 0.f;
  }
  if (tid == kG + 16) bap[0] = b_attn[0];
}

__global__ __launch_bounds__(kTh, 2) void enc_main(
    const float* __restrict__ x,              // (B,9,81) fp32
    const unsigned char* __restrict__ ws,
    float* __restrict__ out_w,                // (B,9,81) fp32
    float* __restrict__ out_h) {              // (B,9,128) fp32
  __shared__ float actT[kKPad][kAStr];            // A^T: [k][b], k<81: w_in, 81..209: h, rest 0
  __shared__ __hip_bfloat16 wch[kKC][kG];         // staged W_t chunk
  __shared__ float red[kNB][8];
  __shared__ float wx_s[16];
  __shared__ float battn_s;

  const int tid = threadIdx.x;
  const int b0  = blockIdx.x * kNB;

  const __hip_bfloat16* Wt = reinterpret_cast<const __hip_bfloat16*>(ws);
  const float* biasp = reinterpret_cast<const float*>(ws + kWsBiasOff);

  if (tid < 16) wx_s[tid] = reinterpret_cast<const float*>(ws + kWsWxOff)[tid];
  if (tid == 16) battn_s = reinterpret_cast<const float*>(ws + kWsBAttnOff)[0];
  // zero h rows (h0 = 0) and K-pad rows
  for (int i = tid; i < (kKPad - kD) * kAStr; i += kTh)
    (&actT[kD][0])[i] = 0.f;
  __syncthreads();

  // ---- pre + softmax once (time-invariant). thread: b = tid>>3, d = (tid&7) + 8m
  const int sb = tid >> 3;
  const int sq = tid & 7;
  float attn[11];
  {
    float lmax = -3.4e38f;
    const size_t xbase = (size_t)(b0 + sb) * kT * kD;
#pragma unroll
    for (int m = 0; m < 11; ++m) {
      int d = sq + 8 * m;
      float s = -3.4e38f;
      if (d < kD) {
        s = battn_s;
#pragma unroll
        for (int t = 0; t < kT; ++t)
          s += x[xbase + t * kD + d] * wx_s[t];
        lmax = fmaxf(lmax, s);
      }
      attn[m] = s;
    }
    red[sb][sq] = lmax;
    __syncthreads();
    float gmax = red[sb][0];
#pragma unroll
    for (int r = 1; r < 8; ++r) gmax = fmaxf(gmax, red[sb][r]);
    __syncthreads();
    float lsum = 0.f;
#pragma unroll
    for (int m = 0; m < 11; ++m) {
      float e = __expf(attn[m] - gmax);   // invalid lanes: exp(-huge) = 0
      attn[m] = e;
      lsum += e;
    }
    red[sb][sq] = lsum;
    __syncthreads();
    float tot = 0.f;
#pragma unroll
    for (int r = 0; r < 8; ++r) tot += red[sb][r];
    float inv = 1.0f / tot;
#pragma unroll
    for (int m = 0; m < 11; ++m) attn[m] *= inv;
  }

  // GEMM mapping: b = (tid&3)*8 + j (j<8); cols p = (tid>>2)*8 + r (r<8)
  const int ib = tid & 3;
  const int iu = tid >> 2;   // u pair {2iu, 2iu+1}
  float bias_r[8];
  {
    const float4* bp = reinterpret_cast<const float4*>(biasp + iu * 8);
    float4 v0 = bp[0], v1 = bp[1];
    bias_r[0]=v0.x; bias_r[1]=v0.y; bias_r[2]=v0.z; bias_r[3]=v0.w;
    bias_r[4]=v1.x; bias_r[5]=v1.y; bias_r[6]=v1.z; bias_r[7]=v1.w;
  }
  float c_reg[8][2];
#pragma unroll
  for (int j = 0; j < 8; ++j) c_reg[j][0] = c_reg[j][1] = 0.f;

  for (int t = 0; t < kT; ++t) {
    // ---- w_in = attn * x_t -> LDS A-matrix + output 0 (fp32)
    {
      const size_t xoff = ((size_t)(b0 + sb) * kT + t) * kD;
#pragma unroll
      for (int m = 0; m < 11; ++m) {
        int d = sq + 8 * m;
        if (d < kD) {
          float w = attn[m] * x[xoff + d];
          actT[d][sb] = w;
          out_w[xoff + d] = w;
        }
      }
    }
    // ---- gates = A @ W_t + bias, chunked over K
    float acc[8][8];
#pragma unroll
    for (int j = 0; j < 8; ++j)
#pragma unroll
      for (int r = 0; r < 8; ++r) acc[j][r] = bias_r[r];

    for (int kc = 0; kc < kKPad / kKC; ++kc) {
      __syncthreads();   // prev chunk's wch reads + (kc==0) actT writes complete
      {
        const uint4* src = reinterpret_cast<const uint4*>(Wt + kc * kKC * kG);
        uint4* dst = reinterpret_cast<uint4*>(&wch[0][0]);
#pragma unroll
        for (int i = 0; i < (kKC * kG * 2 / 16) / kTh; ++i)   // 4
          dst[tid + i * kTh] = src[tid + i * kTh];
      }
      __syncthreads();
      const int kb = kc * kKC;
#pragma unroll
      for (int kk = 0; kk < kKC; kk += 4) {
        float wv[4][8];
#pragma unroll
        for (int xk = 0; xk < 4; ++xk) {
          uint4 wr = *reinterpret_cast<const uint4*>(&wch[kk + xk][iu * 8]);
          wv[xk][0] = bflo(wr.x); wv[xk][1] = bfhi(wr.x);
          wv[xk][2] = bflo(wr.y); wv[xk][3] = bfhi(wr.y);
          wv[xk][4] = bflo(wr.z); wv[xk][5] = bfhi(wr.z);
          wv[xk][6] = bflo(wr.w); wv[xk][7] = bfhi(wr.w);
        }
#pragma unroll
        for (int xk = 0; xk < 4; ++xk) {
          const int k = kb + kk + xk;
          float4 a0 = *reinterpret_cast<const float4*>(&actT[k][ib * 8]);
          float4 a1 = *reinterpret_cast<const float4*>(&actT[k][ib * 8 + 4]);
          float av[8] = {a0.x, a0.y, a0.z, a0.w, a1.x, a1.y, a1.z, a1.w};
#pragma unroll
          for (int j = 0; j < 8; ++j)
#pragma unroll
            for (int r = 0; r < 8; ++r)
              acc[j][r] += av[j] * wv[xk][r];
        }
      }
    }
    __syncthreads();   // all GEMM reads of actT done before h rewrite

    // ---- LSTM pointwise, c in registers; r: 0..3 = i,f,g,o of u0; 4..7 of u0+1
    {
      const int u0 = iu * 2;
#pragma unroll
      for (int j = 0; j < 8; ++j) {
        const int b = ib * 8 + j;
        float c0 = sigf(acc[j][1]) * c_reg[j][0] + sigf(acc[j][0]) * tanhfast(acc[j][2]);
        float h0 = sigf(acc[j][3]) * tanhfast(c0);
        float c1 = sigf(acc[j][5]) * c_reg[j][1] + sigf(acc[j][4]) * tanhfast(acc[j][6]);
        float h1 = sigf(acc[j][7]) * tanhfast(c1);
        c_reg[j][0] = c0; c_reg[j][1] = c1;
        actT[kD + u0][b]     = h0;
        actT[kD + u0 + 1][b] = h1;
        float2 hv;
        hv.x = h0;
        hv.y = h1;
        *reinterpret_cast<float2*>(
            out_h + ((size_t)(b0 + b) * kT + t) * kH + u0) = hv;
      }
    }
  }
}

}  // namespace

extern "C" void kernel_launch(void* const* d_in, const int* in_sizes, int n_in,
                              void* d_out, int out_size, void* d_ws, size_t ws_size,
                              hipStream_t stream) {
  (void)in_sizes; (void)n_in; (void)out_size; (void)ws_size;
  const float* x      = (const float*)d_in[0];
  const float* W_attn = (const float*)d_in[1];
  const float* b_attn = (const float*)d_in[2];
  const float* W_ih   = (const float*)d_in[3];
  const float* W_hh   = (const float*)d_in[4];
  const float* b_ih   = (const float*)d_in[5];
  const float* b_hh   = (const float*)d_in[6];
  float* out_w = (float*)d_out;
  float* out_h = out_w + (size_t)kB * kT * kD;
  unsigned char* ws = (unsigned char*)d_ws;

  hipLaunchKernelGGL(prep_kernel, dim3(64), dim3(256), 0, stream,
                     W_attn, b_attn, W_ih, W_hh, b_ih, b_hh, ws);
  hipLaunchKernelGGL(enc_main, dim3(kB / kNB), dim3(kTh), 0, stream,
                     x, ws, out_w, out_h);
}